// Round 1
// baseline (17853.978 us; speedup 1.0000x reference)
//
#include <hip/hip_runtime.h>
#include <hip/hip_cooperative_groups.h>
#include <math.h>

namespace cg = cooperative_groups;

#define NPTS 4096
#define FD   128
#define NITER 200

__device__ __forceinline__ float sigmoidf_(float x) { return 1.0f / (1.0f + expf(-x)); }

// ---------------- feature MLP kernel: one block (128 thr) per row, side = blockIdx.y ----------------
__global__ void feat_kernel(const float* __restrict__ sn2d, const float* __restrict__ sn3d,
                            const float* __restrict__ pix2d, const float* __restrict__ pts3d,
                            const float* __restrict__ intr,
                            const float* __restrict__ W1i, const float* __restrict__ b1i,
                            const float* __restrict__ W2i, const float* __restrict__ b2i,
                            const float* __restrict__ W3i, const float* __restrict__ b3i,
                            const float* __restrict__ W1p, const float* __restrict__ b1p,
                            const float* __restrict__ W2p, const float* __restrict__ b2p,
                            const float* __restrict__ W3p, const float* __restrict__ b3p,
                            float* __restrict__ f2d, float* __restrict__ f3d,
                            float* __restrict__ x2, float* __restrict__ y2)
{
    const int row  = blockIdx.x;
    const int side = blockIdx.y;
    const int tid  = threadIdx.x;

    __shared__ float xin[6];
    __shared__ float h1s[64];
    __shared__ float h2s[128];
    __shared__ float red[2];

    const float* W1 = side ? W1p : W1i;  const float* B1 = side ? b1p : b1i;
    const float* W2 = side ? W2p : W2i;  const float* B2 = side ? b2p : b2i;
    const float* W3 = side ? W3p : W3i;  const float* B3 = side ? b3p : b3i;

    if (tid == 0) {
        if (side == 0) {
            float a0 = sn2d[row*3+0], a1 = sn2d[row*3+1], a2 = sn2d[row*3+2];
            float n = fmaxf(sqrtf(a0*a0 + a1*a1 + a2*a2), 1e-12f);
            xin[0] = a0/n; xin[1] = a1/n; xin[2] = a2/n;
            float m00 = intr[0], m01 = intr[1], m02 = intr[2];
            float m10 = intr[3], m11 = intr[4], m12 = intr[5];
            float m20 = intr[6], m21 = intr[7], m22 = intr[8];
            float det = m00*(m11*m22 - m12*m21) - m01*(m10*m22 - m12*m20) + m02*(m10*m21 - m11*m20);
            float id = 1.0f/det;
            float i00 = (m11*m22 - m12*m21)*id;
            float i01 = (m02*m21 - m01*m22)*id;
            float i02 = (m01*m12 - m02*m11)*id;
            float i10 = (m12*m20 - m10*m22)*id;
            float i11 = (m00*m22 - m02*m20)*id;
            float i12 = (m02*m10 - m00*m12)*id;
            float i20 = (m10*m21 - m11*m20)*id;
            float i21 = (m01*m20 - m00*m21)*id;
            float i22 = (m00*m11 - m01*m10)*id;
            float px = pix2d[row*2+0], py = pix2d[row*2+1];
            float e0 = i00*px + i01*py + i02;
            float e1 = i10*px + i11*py + i12;
            float e2 = i20*px + i21*py + i22;
            float nb = fmaxf(sqrtf(e0*e0 + e1*e1 + e2*e2), 1e-12f);
            // bea permuted [1,0,2], then l2norm
            xin[3] = e1/nb; xin[4] = e0/nb; xin[5] = e2/nb;
        } else {
            float a0 = sn3d[row*3+0], a1 = sn3d[row*3+1], a2 = sn3d[row*3+2];
            float n = fmaxf(sqrtf(a0*a0 + a1*a1 + a2*a2), 1e-12f);
            xin[0] = a0/n; xin[1] = a1/n; xin[2] = a2/n;
            float p0 = pts3d[row*3+0], p1 = pts3d[row*3+1], p2 = pts3d[row*3+2];
            float pn = fmaxf(sqrtf(p0*p0 + p1*p1 + p2*p2), 1e-12f);
            xin[3] = p0/pn; xin[4] = p1/pn; xin[5] = p2/pn;
        }
    }
    __syncthreads();
    if (tid < 64) {
        float a = B1[tid];
        #pragma unroll
        for (int k = 0; k < 6; ++k) a += xin[k] * W1[tid*6 + k];
        h1s[tid] = sigmoidf_(a);
    }
    __syncthreads();
    {
        float a = B2[tid];
        #pragma unroll 8
        for (int k = 0; k < 64; ++k) a += h1s[k] * W2[tid*64 + k];
        h2s[tid] = sigmoidf_(a);
    }
    __syncthreads();
    float a = B3[tid];
    #pragma unroll 8
    for (int k = 0; k < 128; ++k) a += h2s[k] * W3[tid*128 + k];
    float o = sigmoidf_(a);

    float ss = o*o;
    #pragma unroll
    for (int m = 32; m >= 1; m >>= 1) ss += __shfl_xor(ss, m, 64);
    if ((tid & 63) == 0) red[tid >> 6] = ss;
    __syncthreads();
    float tot = red[0] + red[1];
    float n = fmaxf(sqrtf(tot), 1e-12f);
    float f = o / n;
    (side ? f3d : f2d)[row*FD + tid] = f;

    // x2/y2 = sum of squares of the *normalized* features (as the reference computes)
    float ss2 = f*f;
    #pragma unroll
    for (int m = 32; m >= 1; m >>= 1) ss2 += __shfl_xor(ss2, m, 64);
    __syncthreads();
    if ((tid & 63) == 0) red[tid >> 6] = ss2;
    __syncthreads();
    if (tid == 0) (side ? y2 : x2)[row] = red[0] + red[1];
}

// ---------------- cost kernel: 64x64 tile per block (256 thr), K = exp(-M/0.1) into d_out ----------------
__global__ void __launch_bounds__(256) cost_kernel(const float* __restrict__ f2d, const float* __restrict__ f3d,
                                                   const float* __restrict__ x2, const float* __restrict__ y2,
                                                   float* __restrict__ K)
{
    __shared__ float As[128][64];  // As[k][i] = f2d[i0+i][k]
    __shared__ float Bs[128][64];  // Bs[k][j] = f3d[j0+j][k]
    const int tid = threadIdx.x;
    const int i0 = blockIdx.y * 64;
    const int j0 = blockIdx.x * 64;

    {
        int r0 = tid >> 5;             // 0..7
        int c  = (tid & 31) * 4;       // 0..124
        for (int rr = r0; rr < 64; rr += 8) {
            float4 av = *(const float4*)(f2d + (size_t)(i0+rr)*FD + c);
            As[c+0][rr] = av.x; As[c+1][rr] = av.y; As[c+2][rr] = av.z; As[c+3][rr] = av.w;
            float4 bv = *(const float4*)(f3d + (size_t)(j0+rr)*FD + c);
            Bs[c+0][rr] = bv.x; Bs[c+1][rr] = bv.y; Bs[c+2][rr] = bv.z; Bs[c+3][rr] = bv.w;
        }
    }
    __syncthreads();

    const int tx = tid & 15;   // j
    const int ty = tid >> 4;   // i
    float acc[4][4] = {};
    for (int k = 0; k < 128; ++k) {
        float4 av = *(const float4*)&As[k][ty*4];
        float4 bv = *(const float4*)&Bs[k][tx*4];
        float aa[4] = {av.x, av.y, av.z, av.w};
        float bb[4] = {bv.x, bv.y, bv.z, bv.w};
        #pragma unroll
        for (int i = 0; i < 4; ++i)
            #pragma unroll
            for (int j = 0; j < 4; ++j)
                acc[i][j] += aa[i] * bb[j];
    }

    #pragma unroll
    for (int i = 0; i < 4; ++i) {
        int gi = i0 + ty*4 + i;
        float xv = x2[gi];
        float res[4];
        #pragma unroll
        for (int j = 0; j < 4; ++j) {
            int gj = j0 + tx*4 + j;
            float d2 = xv + y2[gj] - 2.0f * acc[i][j];
            d2 = fmaxf(d2, 1e-12f);
            float M = sqrtf(d2);
            res[j] = expf(-M / 0.1f);
        }
        float4 o = make_float4(res[0], res[1], res[2], res[3]);
        *(float4*)(K + (size_t)gi*NPTS + j0 + tx*4) = o;
    }
}

// ---------------- persistent cooperative Sinkhorn: 256 blocks x 1024 thr ----------------
__global__ void __launch_bounds__(1024) sinkhorn_kernel(float* __restrict__ K,
                                                        float* __restrict__ u,
                                                        float* __restrict__ v)
{
    cg::grid_group grid = cg::this_grid();
    const int tid = threadIdx.x;
    const int bid = blockIdx.x;    // 0..255
    const float rC = 1.0f / 4096.0f;
    const float cC = 1.0f / 4096.0f;
    __shared__ float red[256];

    // u = 1
    {
        int gi = bid*1024 + tid;
        if (gi < NPTS) u[gi] = 1.0f;
    }
    grid.sync();

    for (int it = 0; it <= NITER; ++it) {
        // half A: v_j = c / sum_i K[i][j] * u[i]; this block owns 16 columns
        {
            const int c0  = bid * 16;
            const int col = tid & 15;
            const int rq  = tid >> 4;   // 0..63
            float acc = 0.0f;
            const float* Kp = K + c0 + col;
            #pragma unroll 4
            for (int r = rq; r < NPTS; r += 64)
                acc += Kp[(size_t)r * NPTS] * u[r];
            acc += __shfl_xor(acc, 16, 64);
            acc += __shfl_xor(acc, 32, 64);
            const int lane = tid & 63, wid = tid >> 6;
            if (lane < 16) red[wid*16 + lane] = acc;
            __syncthreads();
            if (tid < 16) {
                float s = 0.0f;
                #pragma unroll
                for (int w = 0; w < 16; ++w) s += red[w*16 + tid];
                v[c0 + tid] = cC / s;
            }
        }
        grid.sync();
        if (it == NITER) break;     // 201 A-halves, 200 B-halves

        // half B: u_i = r / sum_j K[i][j] * v[j]; this block owns 16 rows (one per wave)
        {
            const int wid = tid >> 6, lane = tid & 63;
            const int r = bid*16 + wid;
            const float4* Kr = (const float4*)(K + (size_t)r * NPTS);
            const float4* v4 = (const float4*)v;
            float acc = 0.0f;
            #pragma unroll 4
            for (int s = 0; s < 16; ++s) {
                float4 kk = Kr[lane + 64*s];
                float4 vv = v4[lane + 64*s];
                acc += kk.x*vv.x + kk.y*vv.y + kk.z*vv.z + kk.w*vv.w;
            }
            #pragma unroll
            for (int m = 32; m >= 1; m >>= 1) acc += __shfl_xor(acc, m, 64);
            if (lane == 0) u[r] = rC / acc;
        }
        grid.sync();
    }

    // final: P = u[:,None] * K * v[None,:] in place over d_out
    {
        const int wid = tid >> 6, lane = tid & 63;
        const int r = bid*16 + wid;
        const float ur = u[r];
        float4* Kr = (float4*)(K + (size_t)r * NPTS);
        const float4* v4 = (const float4*)v;
        #pragma unroll 4
        for (int s = 0; s < 16; ++s) {
            float4 kk = Kr[lane + 64*s];
            float4 vv = v4[lane + 64*s];
            kk.x *= ur * vv.x; kk.y *= ur * vv.y; kk.z *= ur * vv.z; kk.w *= ur * vv.w;
            Kr[lane + 64*s] = kk;
        }
    }
}

extern "C" void kernel_launch(void* const* d_in, const int* in_sizes, int n_in,
                              void* d_out, int out_size, void* d_ws, size_t ws_size,
                              hipStream_t stream)
{
    (void)in_sizes; (void)n_in; (void)out_size; (void)ws_size;
    const float* sn2d  = (const float*)d_in[0];
    const float* sn3d  = (const float*)d_in[1];
    const float* pix2d = (const float*)d_in[2];
    const float* pts3d = (const float*)d_in[3];
    const float* intr  = (const float*)d_in[4];
    const float* W1i = (const float*)d_in[5];  const float* b1i = (const float*)d_in[6];
    const float* W2i = (const float*)d_in[7];  const float* b2i = (const float*)d_in[8];
    const float* W3i = (const float*)d_in[9];  const float* b3i = (const float*)d_in[10];
    const float* W1p = (const float*)d_in[11]; const float* b1p = (const float*)d_in[12];
    const float* W2p = (const float*)d_in[13]; const float* b2p = (const float*)d_in[14];
    const float* W3p = (const float*)d_in[15]; const float* b3p = (const float*)d_in[16];

    float* ws  = (float*)d_ws;
    float* f2d = ws;                       // 4096*128
    float* f3d = f2d + NPTS*FD;            // 4096*128
    float* x2  = f3d + NPTS*FD;            // 4096
    float* y2  = x2 + NPTS;                // 4096
    float* u   = y2 + NPTS;                // 4096
    float* v   = u  + NPTS;                // 4096
    float* K   = (float*)d_out;            // 4096*4096, scaled in place to P at the end

    feat_kernel<<<dim3(NPTS, 2), 128, 0, stream>>>(sn2d, sn3d, pix2d, pts3d, intr,
        W1i, b1i, W2i, b2i, W3i, b3i, W1p, b1p, W2p, b2p, W3p, b3p,
        f2d, f3d, x2, y2);

    cost_kernel<<<dim3(64, 64), 256, 0, stream>>>(f2d, f3d, x2, y2, K);

    void* args[] = { (void*)&K, (void*)&u, (void*)&v };
    hipLaunchCooperativeKernel((const void*)sinkhorn_kernel, dim3(256), dim3(1024), args, 0, stream);
}

// Round 3
// 14830.276 us; speedup vs baseline: 1.2039x; 1.2039x over previous
//
#include <hip/hip_runtime.h>
#include <hip/hip_cooperative_groups.h>
#include <math.h>

namespace cg = cooperative_groups;

#define NPTS 4096
#define FD   128
#define NITER 200
#define INVN (1.0f / 4096.0f)

typedef unsigned int uint32;

__device__ __forceinline__ float sigmoidf_(float x) { return 1.0f / (1.0f + expf(-x)); }

__device__ __forceinline__ unsigned short f2bf(float f) {
    uint32 x = __float_as_uint(f);
    uint32 r = x + 0x7fffu + ((x >> 16) & 1u);   // RNE; inputs are positive finite
    return (unsigned short)(r >> 16);
}

__device__ __forceinline__ float wave_red_sum(float a) {
    #pragma unroll
    for (int m = 32; m >= 1; m >>= 1) a += __shfl_xor(a, m, 64);
    return a;
}

// per-lane partial of dot(Krow[0..4095] (bf16), x[0..4095] (fp32)); caller wave-reduces
__device__ __forceinline__ float bf16_row_dot(const unsigned short* __restrict__ Krow,
                                              const float* __restrict__ x,
                                              int lane, int first)
{
    const float4* kp = (const float4*)Krow;   // 8 bf16 per float4
    const float4* xp = (const float4*)x;
    float acc = 0.0f;
    #pragma unroll
    for (int s = 0; s < 8; ++s) {
        int i = s*64 + lane;                  // 16B chunk index
        float4 kk = kp[i];
        const uint32* kw = (const uint32*)&kk;
        float xx[8];
        if (first) {
            #pragma unroll
            for (int q = 0; q < 8; ++q) xx[q] = 1.0f;
        } else {
            float4 x0 = xp[i*2], x1 = xp[i*2 + 1];
            xx[0]=x0.x; xx[1]=x0.y; xx[2]=x0.z; xx[3]=x0.w;
            xx[4]=x1.x; xx[5]=x1.y; xx[6]=x1.z; xx[7]=x1.w;
        }
        #pragma unroll
        for (int q = 0; q < 4; ++q) {
            acc += __uint_as_float(kw[q] << 16)         * xx[2*q]
                 + __uint_as_float(kw[q] & 0xffff0000u) * xx[2*q+1];
        }
    }
    return acc;
}

__device__ __forceinline__ float f32_row_dot(const float* __restrict__ Krow,
                                             const float* __restrict__ x, int lane)
{
    const float4* kp = (const float4*)Krow;
    const float4* xp = (const float4*)x;
    float acc = 0.0f;
    #pragma unroll
    for (int s = 0; s < 16; ++s) {
        int i = s*64 + lane;
        float4 kk = kp[i], xx = xp[i];
        acc += kk.x*xx.x + kk.y*xx.y + kk.z*xx.z + kk.w*xx.w;
    }
    return acc;
}

__device__ __forceinline__ float f32_col_dot(const float* __restrict__ K,
                                             const float* __restrict__ u,
                                             int col, int lane, int first)
{
    float acc = 0.0f;
    for (int i = lane; i < NPTS; i += 64)
        acc += K[(size_t)i*NPTS + col] * (first ? 1.0f : u[i]);
    return acc;
}

// ---------------- feature MLP kernel: one block (128 thr) per row, side = blockIdx.y ----------------
__global__ void feat_kernel(const float* __restrict__ sn2d, const float* __restrict__ sn3d,
                            const float* __restrict__ pix2d, const float* __restrict__ pts3d,
                            const float* __restrict__ intr,
                            const float* __restrict__ W1i, const float* __restrict__ b1i,
                            const float* __restrict__ W2i, const float* __restrict__ b2i,
                            const float* __restrict__ W3i, const float* __restrict__ b3i,
                            const float* __restrict__ W1p, const float* __restrict__ b1p,
                            const float* __restrict__ W2p, const float* __restrict__ b2p,
                            const float* __restrict__ W3p, const float* __restrict__ b3p,
                            float* __restrict__ f2d, float* __restrict__ f3d,
                            float* __restrict__ x2, float* __restrict__ y2)
{
    const int row  = blockIdx.x;
    const int side = blockIdx.y;
    const int tid  = threadIdx.x;

    __shared__ float xin[6];
    __shared__ float h1s[64];
    __shared__ float h2s[128];
    __shared__ float red[2];

    const float* W1 = side ? W1p : W1i;  const float* B1 = side ? b1p : b1i;
    const float* W2 = side ? W2p : W2i;  const float* B2 = side ? b2p : b2i;
    const float* W3 = side ? W3p : W3i;  const float* B3 = side ? b3p : b3i;

    if (tid == 0) {
        if (side == 0) {
            float a0 = sn2d[row*3+0], a1 = sn2d[row*3+1], a2 = sn2d[row*3+2];
            float n = fmaxf(sqrtf(a0*a0 + a1*a1 + a2*a2), 1e-12f);
            xin[0] = a0/n; xin[1] = a1/n; xin[2] = a2/n;
            float m00 = intr[0], m01 = intr[1], m02 = intr[2];
            float m10 = intr[3], m11 = intr[4], m12 = intr[5];
            float m20 = intr[6], m21 = intr[7], m22 = intr[8];
            float det = m00*(m11*m22 - m12*m21) - m01*(m10*m22 - m12*m20) + m02*(m10*m21 - m11*m20);
            float id = 1.0f/det;
            float i00 = (m11*m22 - m12*m21)*id;
            float i01 = (m02*m21 - m01*m22)*id;
            float i02 = (m01*m12 - m02*m11)*id;
            float i10 = (m12*m20 - m10*m22)*id;
            float i11 = (m00*m22 - m02*m20)*id;
            float i12 = (m02*m10 - m00*m12)*id;
            float i20 = (m10*m21 - m11*m20)*id;
            float i21 = (m01*m20 - m00*m21)*id;
            float i22 = (m00*m11 - m01*m10)*id;
            float px = pix2d[row*2+0], py = pix2d[row*2+1];
            float e0 = i00*px + i01*py + i02;
            float e1 = i10*px + i11*py + i12;
            float e2 = i20*px + i21*py + i22;
            float nb = fmaxf(sqrtf(e0*e0 + e1*e1 + e2*e2), 1e-12f);
            xin[3] = e1/nb; xin[4] = e0/nb; xin[5] = e2/nb;
        } else {
            float a0 = sn3d[row*3+0], a1 = sn3d[row*3+1], a2 = sn3d[row*3+2];
            float n = fmaxf(sqrtf(a0*a0 + a1*a1 + a2*a2), 1e-12f);
            xin[0] = a0/n; xin[1] = a1/n; xin[2] = a2/n;
            float p0 = pts3d[row*3+0], p1 = pts3d[row*3+1], p2 = pts3d[row*3+2];
            float pn = fmaxf(sqrtf(p0*p0 + p1*p1 + p2*p2), 1e-12f);
            xin[3] = p0/pn; xin[4] = p1/pn; xin[5] = p2/pn;
        }
    }
    __syncthreads();
    if (tid < 64) {
        float a = B1[tid];
        #pragma unroll
        for (int k = 0; k < 6; ++k) a += xin[k] * W1[tid*6 + k];
        h1s[tid] = sigmoidf_(a);
    }
    __syncthreads();
    {
        float a = B2[tid];
        #pragma unroll 8
        for (int k = 0; k < 64; ++k) a += h1s[k] * W2[tid*64 + k];
        h2s[tid] = sigmoidf_(a);
    }
    __syncthreads();
    float a = B3[tid];
    #pragma unroll 8
    for (int k = 0; k < 128; ++k) a += h2s[k] * W3[tid*128 + k];
    float o = sigmoidf_(a);

    float ss = o*o;
    #pragma unroll
    for (int m = 32; m >= 1; m >>= 1) ss += __shfl_xor(ss, m, 64);
    if ((tid & 63) == 0) red[tid >> 6] = ss;
    __syncthreads();
    float tot = red[0] + red[1];
    float n = fmaxf(sqrtf(tot), 1e-12f);
    float f = o / n;
    (side ? f3d : f2d)[row*FD + tid] = f;

    float ss2 = f*f;
    #pragma unroll
    for (int m = 32; m >= 1; m >>= 1) ss2 += __shfl_xor(ss2, m, 64);
    __syncthreads();
    if ((tid & 63) == 0) red[tid >> 6] = ss2;
    __syncthreads();
    if (tid == 0) (side ? y2 : x2)[row] = red[0] + red[1];
}

// ---------------- cost kernel: 64x64 tile per block; writes fp32 K, bf16 Kb (row), bf16 KbT (col) ----------------
__global__ void __launch_bounds__(256) cost_kernel(const float* __restrict__ f2d, const float* __restrict__ f3d,
                                                   const float* __restrict__ x2, const float* __restrict__ y2,
                                                   float* __restrict__ K,
                                                   unsigned short* __restrict__ Kb,
                                                   unsigned short* __restrict__ KbT,
                                                   int wantB, int wantT)
{
    __shared__ float As[128][64];
    __shared__ float Bs[128][64];
    const int tid = threadIdx.x;
    const int i0 = blockIdx.y * 64;
    const int j0 = blockIdx.x * 64;

    {
        int r0 = tid >> 5;
        int c  = (tid & 31) * 4;
        for (int rr = r0; rr < 64; rr += 8) {
            float4 av = *(const float4*)(f2d + (size_t)(i0+rr)*FD + c);
            As[c+0][rr] = av.x; As[c+1][rr] = av.y; As[c+2][rr] = av.z; As[c+3][rr] = av.w;
            float4 bv = *(const float4*)(f3d + (size_t)(j0+rr)*FD + c);
            Bs[c+0][rr] = bv.x; Bs[c+1][rr] = bv.y; Bs[c+2][rr] = bv.z; Bs[c+3][rr] = bv.w;
        }
    }
    __syncthreads();

    const int tx = tid & 15;
    const int ty = tid >> 4;
    float acc[4][4] = {};
    for (int k = 0; k < 128; ++k) {
        float4 av = *(const float4*)&As[k][ty*4];
        float4 bv = *(const float4*)&Bs[k][tx*4];
        float aa[4] = {av.x, av.y, av.z, av.w};
        float bb[4] = {bv.x, bv.y, bv.z, bv.w};
        #pragma unroll
        for (int i = 0; i < 4; ++i)
            #pragma unroll
            for (int j = 0; j < 4; ++j)
                acc[i][j] += aa[i] * bb[j];
    }

    float kv[4][4];
    #pragma unroll
    for (int i = 0; i < 4; ++i) {
        int gi = i0 + ty*4 + i;
        float xv = x2[gi];
        #pragma unroll
        for (int j = 0; j < 4; ++j) {
            int gj = j0 + tx*4 + j;
            float d2 = xv + y2[gj] - 2.0f * acc[i][j];
            d2 = fmaxf(d2, 1e-12f);
            kv[i][j] = expf(-sqrtf(d2) * 10.0f);
        }
    }

    #pragma unroll
    for (int i = 0; i < 4; ++i) {
        int gi = i0 + ty*4 + i;
        *(float4*)(K + (size_t)gi*NPTS + j0 + tx*4) = make_float4(kv[i][0], kv[i][1], kv[i][2], kv[i][3]);
        if (wantB) {
            uint32 lo = (uint32)f2bf(kv[i][0]) | ((uint32)f2bf(kv[i][1]) << 16);
            uint32 hi = (uint32)f2bf(kv[i][2]) | ((uint32)f2bf(kv[i][3]) << 16);
            uint2 p; p.x = lo; p.y = hi;
            *(uint2*)(Kb + (size_t)gi*NPTS + j0 + tx*4) = p;
        }
    }
    if (wantT) {
        #pragma unroll
        for (int j = 0; j < 4; ++j) {
            int gj = j0 + tx*4 + j;
            uint32 lo = (uint32)f2bf(kv[0][j]) | ((uint32)f2bf(kv[1][j]) << 16);
            uint32 hi = (uint32)f2bf(kv[2][j]) | ((uint32)f2bf(kv[3][j]) << 16);
            uint2 p; p.x = lo; p.y = hi;
            *(uint2*)(KbT + (size_t)gj*NPTS + i0 + ty*4) = p;
        }
    }
}

// ---------------- persistent cooperative Sinkhorn: 256 blocks x 1024 thr (proven shape) ----------------
// wave w of block b owns row/col index r = b*16 + w for both halves and the final scale.
__global__ void __launch_bounds__(1024) sinkhorn_kernel(float* __restrict__ K,
                                                        const unsigned short* __restrict__ Kb,
                                                        const unsigned short* __restrict__ KbT,
                                                        float* __restrict__ u,
                                                        float* __restrict__ v,
                                                        int modeA, int modeB)
{
    cg::grid_group grid = cg::this_grid();
    const int tid  = threadIdx.x;
    const int w    = tid >> 6;
    const int lane = tid & 63;
    const int r    = blockIdx.x * 16 + w;

    for (int it = 0; it <= NITER; ++it) {
        // half A: v_r = c / dot(K[:,r], u)
        {
            float acc = modeA ? bf16_row_dot(KbT + (size_t)r * NPTS, u, lane, it == 0)
                              : f32_col_dot(K, u, r, lane, it == 0);
            acc = wave_red_sum(acc);
            if (lane == 0) v[r] = INVN / acc;
        }
        grid.sync();
        if (it == NITER) break;   // 201 A-halves, 200 B-halves

        // half B: u_r = r / dot(K[r,:], v)
        {
            float acc = modeB ? bf16_row_dot(Kb + (size_t)r * NPTS, v, lane, 0)
                              : f32_row_dot(K + (size_t)r * NPTS, v, lane);
            acc = wave_red_sum(acc);
            if (lane == 0) u[r] = INVN / acc;
        }
        grid.sync();
    }

    // final: P = u[:,None] * K * v[None,:] in place over d_out (fp32 K, exact)
    {
        const float ur = u[r];
        float4* kp = (float4*)(K + (size_t)r * NPTS);
        const float4* vp = (const float4*)v;
        #pragma unroll
        for (int s = 0; s < 16; ++s) {
            int e4 = s * 64 + lane;
            float4 kk = kp[e4], vv = vp[e4];
            kk.x *= ur * vv.x; kk.y *= ur * vv.y; kk.z *= ur * vv.z; kk.w *= ur * vv.w;
            kp[e4] = kk;
        }
    }
}

// ---------------- non-cooperative fallback kernels (used only if coop launch fails) ----------------
__global__ void __launch_bounds__(1024) stepA_kernel(const float* __restrict__ K,
                                                     const unsigned short* __restrict__ KbT,
                                                     const float* __restrict__ u, float* __restrict__ v,
                                                     int first, int modeA)
{
    const int w = threadIdx.x >> 6, lane = threadIdx.x & 63;
    const int r = blockIdx.x * 16 + w;
    float acc = modeA ? bf16_row_dot(KbT + (size_t)r * NPTS, u, lane, first)
                      : f32_col_dot(K, u, r, lane, first);
    acc = wave_red_sum(acc);
    if (lane == 0) v[r] = INVN / acc;
}

__global__ void __launch_bounds__(1024) stepB_kernel(const float* __restrict__ K,
                                                     const unsigned short* __restrict__ Kb,
                                                     const float* __restrict__ v, float* __restrict__ u,
                                                     int modeB)
{
    const int w = threadIdx.x >> 6, lane = threadIdx.x & 63;
    const int r = blockIdx.x * 16 + w;
    float acc = modeB ? bf16_row_dot(Kb + (size_t)r * NPTS, v, lane, 0)
                      : f32_row_dot(K + (size_t)r * NPTS, v, lane);
    acc = wave_red_sum(acc);
    if (lane == 0) u[r] = INVN / acc;
}

__global__ void __launch_bounds__(1024) final_kernel(float* __restrict__ K,
                                                     const float* __restrict__ u,
                                                     const float* __restrict__ v)
{
    const int w = threadIdx.x >> 6, lane = threadIdx.x & 63;
    const int r = blockIdx.x * 16 + w;
    const float ur = u[r];
    float4* kp = (float4*)(K + (size_t)r * NPTS);
    const float4* vp = (const float4*)v;
    #pragma unroll
    for (int s = 0; s < 16; ++s) {
        int e4 = s * 64 + lane;
        float4 kk = kp[e4], vv = vp[e4];
        kk.x *= ur * vv.x; kk.y *= ur * vv.y; kk.z *= ur * vv.z; kk.w *= ur * vv.w;
        kp[e4] = kk;
    }
}

extern "C" void kernel_launch(void* const* d_in, const int* in_sizes, int n_in,
                              void* d_out, int out_size, void* d_ws, size_t ws_size,
                              hipStream_t stream)
{
    (void)in_sizes; (void)n_in; (void)out_size;
    const float* sn2d  = (const float*)d_in[0];
    const float* sn3d  = (const float*)d_in[1];
    const float* pix2d = (const float*)d_in[2];
    const float* pts3d = (const float*)d_in[3];
    const float* intr  = (const float*)d_in[4];
    const float* W1i = (const float*)d_in[5];  const float* b1i = (const float*)d_in[6];
    const float* W2i = (const float*)d_in[7];  const float* b2i = (const float*)d_in[8];
    const float* W3i = (const float*)d_in[9];  const float* b3i = (const float*)d_in[10];
    const float* W1p = (const float*)d_in[11]; const float* b1p = (const float*)d_in[12];
    const float* W2p = (const float*)d_in[13]; const float* b2p = (const float*)d_in[14];
    const float* W3p = (const float*)d_in[15]; const float* b3p = (const float*)d_in[16];

    float* ws  = (float*)d_ws;
    float* f2d = ws;                       // 4096*128
    float* f3d = f2d + NPTS*FD;            // 4096*128
    float* x2  = f3d + NPTS*FD;            // 4096
    float* y2  = x2 + NPTS;                // 4096
    float* u   = y2 + NPTS;                // 4096
    float* v   = u  + NPTS;                // 4096
    unsigned short* KbT = (unsigned short*)(v + NPTS);   // 4096*4096 bf16 = 33.55 MB
    unsigned short* Kb  = KbT + (size_t)NPTS*NPTS;       // 4096*4096 bf16 = 33.55 MB
    float* K   = (float*)d_out;            // fp32 K, scaled in place to P at the end

    const size_t base_bytes = (size_t)(2*NPTS*FD + 4*NPTS) * 4;
    const size_t bf16_bytes = (size_t)NPTS * NPTS * 2;
    int modeA = (ws_size >= base_bytes + bf16_bytes)   ? 1 : 0;   // KbT fits
    int modeB = (ws_size >= base_bytes + 2*bf16_bytes) ? 1 : 0;   // Kb too

    feat_kernel<<<dim3(NPTS, 2), 128, 0, stream>>>(sn2d, sn3d, pix2d, pts3d, intr,
        W1i, b1i, W2i, b2i, W3i, b3i, W1p, b1p, W2p, b2p, W3p, b3p,
        f2d, f3d, x2, y2);

    cost_kernel<<<dim3(64, 64), 256, 0, stream>>>(f2d, f3d, x2, y2, K, Kb, KbT, modeB, modeA);

    void* args[] = { (void*)&K, (void*)&Kb, (void*)&KbT, (void*)&u, (void*)&v,
                     (void*)&modeA, (void*)&modeB };
    hipError_t err = hipLaunchCooperativeKernel((const void*)sinkhorn_kernel,
                                                dim3(256), dim3(1024), args, 0, stream);
    if (err != hipSuccess) {
        // non-cooperative fallback: same math, one launch per half-step
        stepA_kernel<<<256, 1024, 0, stream>>>(K, KbT, u, v, 1, modeA);
        for (int i = 0; i < NITER; ++i) {
            stepB_kernel<<<256, 1024, 0, stream>>>(K, Kb, v, u, modeB);
            stepA_kernel<<<256, 1024, 0, stream>>>(K, KbT, u, v, 0, modeA);
        }
        final_kernel<<<256, 1024, 0, stream>>>(K, u, v);
    }
}

// Round 4
// 2947.095 us; speedup vs baseline: 6.0582x; 5.0322x over previous
//
#include <hip/hip_runtime.h>
#include <math.h>

#define NPTS 4096
#define FD   128
#define NITER 200
#define INVN (1.0f / 4096.0f)
#define NBLK 256
#define SMEM_BYTES (NPTS*4 + 16*NPTS*2)   // 16 KB xs + 128 KB Kb rows = 147456 B

typedef unsigned int uint32;

__device__ __forceinline__ float sigmoidf_(float x) { return 1.0f / (1.0f + expf(-x)); }

__device__ __forceinline__ unsigned short f2bf(float f) {
    uint32 x = __float_as_uint(f);
    uint32 r = x + 0x7fffu + ((x >> 16) & 1u);   // RNE; inputs are positive finite
    return (unsigned short)(r >> 16);
}

__device__ __forceinline__ float wave_red_sum(float a) {
    #pragma unroll
    for (int m = 32; m >= 1; m >>= 1) a += __shfl_xor(a, m, 64);
    return a;
}

// ---- lightweight grid barrier: packed word = (gen<<12) | count; no L2 flush/inv ----
__device__ __forceinline__ void gbar(unsigned* bar, int tid) {
    asm volatile("s_waitcnt vmcnt(0)" ::: "memory");   // drain this wave's coherent stores
    __syncthreads();                                   // all waves of block drained + arrived
    if (tid == 0) {
        unsigned old = __hip_atomic_fetch_add(bar, 1u, __ATOMIC_RELAXED, __HIP_MEMORY_SCOPE_AGENT);
        unsigned g = old >> 12;
        if ((old & 0xFFFu) == (unsigned)(NBLK - 1)) {
            // reset count AND bump generation in one atomic (no reset race)
            __hip_atomic_fetch_add(bar, (1u << 12) - (unsigned)NBLK,
                                   __ATOMIC_RELAXED, __HIP_MEMORY_SCOPE_AGENT);
        } else {
            int guard = 0;
            while ((__hip_atomic_load(bar, __ATOMIC_RELAXED, __HIP_MEMORY_SCOPE_AGENT) >> 12) == g) {
                __builtin_amdgcn_s_sleep(8);
                if (++guard > (1 << 22)) break;        // hang insurance only
            }
        }
    }
    __syncthreads();
}

// per-lane partial of dot(bf16 row in GLOBAL, xs in LDS); caller wave-reduces
__device__ __forceinline__ float dot_bf16_g(const unsigned short* __restrict__ Krow,
                                            const float* xs, int lane)
{
    const uint4* kp = (const uint4*)Krow;
    float acc = 0.0f;
    #pragma unroll
    for (int s = 0; s < 8; ++s) {
        int c = s * 64 + lane;
        uint4 kk = kp[c];
        const float* xp = xs + c * 8;
        float4 x0 = *(const float4*)xp;
        float4 x1 = *(const float4*)(xp + 4);
        float xx[8] = {x0.x, x0.y, x0.z, x0.w, x1.x, x1.y, x1.z, x1.w};
        uint32 kw[4] = {kk.x, kk.y, kk.z, kk.w};
        #pragma unroll
        for (int q = 0; q < 4; ++q) {
            acc += __uint_as_float(kw[q] << 16)          * xx[2*q]
                 + __uint_as_float(kw[q] & 0xffff0000u)  * xx[2*q+1];
        }
    }
    return acc;
}

// round-3 helpers for the non-cooperative fallback path
__device__ __forceinline__ float bf16_row_dot(const unsigned short* __restrict__ Krow,
                                              const float* __restrict__ x,
                                              int lane, int first)
{
    const float4* kp = (const float4*)Krow;
    const float4* xp = (const float4*)x;
    float acc = 0.0f;
    #pragma unroll
    for (int s = 0; s < 8; ++s) {
        int i = s*64 + lane;
        float4 kk = kp[i];
        const uint32* kw = (const uint32*)&kk;
        float xx[8];
        if (first) {
            #pragma unroll
            for (int q = 0; q < 8; ++q) xx[q] = 1.0f;
        } else {
            float4 x0 = xp[i*2], x1 = xp[i*2 + 1];
            xx[0]=x0.x; xx[1]=x0.y; xx[2]=x0.z; xx[3]=x0.w;
            xx[4]=x1.x; xx[5]=x1.y; xx[6]=x1.z; xx[7]=x1.w;
        }
        #pragma unroll
        for (int q = 0; q < 4; ++q) {
            acc += __uint_as_float(kw[q] << 16)         * xx[2*q]
                 + __uint_as_float(kw[q] & 0xffff0000u) * xx[2*q+1];
        }
    }
    return acc;
}

__device__ __forceinline__ float f32_row_dot(const float* __restrict__ Krow,
                                             const float* __restrict__ x, int lane)
{
    const float4* kp = (const float4*)Krow;
    const float4* xp = (const float4*)x;
    float acc = 0.0f;
    #pragma unroll
    for (int s = 0; s < 16; ++s) {
        int i = s*64 + lane;
        float4 kk = kp[i], xx = xp[i];
        acc += kk.x*xx.x + kk.y*xx.y + kk.z*xx.z + kk.w*xx.w;
    }
    return acc;
}

__device__ __forceinline__ float f32_col_dot(const float* __restrict__ K,
                                             const float* __restrict__ u,
                                             int col, int lane, int first)
{
    float acc = 0.0f;
    for (int i = lane; i < NPTS; i += 64)
        acc += K[(size_t)i*NPTS + col] * (first ? 1.0f : u[i]);
    return acc;
}

// ---------------- feature MLP kernel: one block (128 thr) per row, side = blockIdx.y ----------------
__global__ void feat_kernel(const float* __restrict__ sn2d, const float* __restrict__ sn3d,
                            const float* __restrict__ pix2d, const float* __restrict__ pts3d,
                            const float* __restrict__ intr,
                            const float* __restrict__ W1i, const float* __restrict__ b1i,
                            const float* __restrict__ W2i, const float* __restrict__ b2i,
                            const float* __restrict__ W3i, const float* __restrict__ b3i,
                            const float* __restrict__ W1p, const float* __restrict__ b1p,
                            const float* __restrict__ W2p, const float* __restrict__ b2p,
                            const float* __restrict__ W3p, const float* __restrict__ b3p,
                            float* __restrict__ f2d, float* __restrict__ f3d,
                            float* __restrict__ x2, float* __restrict__ y2)
{
    const int row  = blockIdx.x;
    const int side = blockIdx.y;
    const int tid  = threadIdx.x;

    __shared__ float xin[6];
    __shared__ float h1s[64];
    __shared__ float h2s[128];
    __shared__ float red[2];

    const float* W1 = side ? W1p : W1i;  const float* B1 = side ? b1p : b1i;
    const float* W2 = side ? W2p : W2i;  const float* B2 = side ? b2p : b2i;
    const float* W3 = side ? W3p : W3i;  const float* B3 = side ? b3p : b3i;

    if (tid == 0) {
        if (side == 0) {
            float a0 = sn2d[row*3+0], a1 = sn2d[row*3+1], a2 = sn2d[row*3+2];
            float n = fmaxf(sqrtf(a0*a0 + a1*a1 + a2*a2), 1e-12f);
            xin[0] = a0/n; xin[1] = a1/n; xin[2] = a2/n;
            float m00 = intr[0], m01 = intr[1], m02 = intr[2];
            float m10 = intr[3], m11 = intr[4], m12 = intr[5];
            float m20 = intr[6], m21 = intr[7], m22 = intr[8];
            float det = m00*(m11*m22 - m12*m21) - m01*(m10*m22 - m12*m20) + m02*(m10*m21 - m11*m20);
            float id = 1.0f/det;
            float i00 = (m11*m22 - m12*m21)*id;
            float i01 = (m02*m21 - m01*m22)*id;
            float i02 = (m01*m12 - m02*m11)*id;
            float i10 = (m12*m20 - m10*m22)*id;
            float i11 = (m00*m22 - m02*m20)*id;
            float i12 = (m02*m10 - m00*m12)*id;
            float i20 = (m10*m21 - m11*m20)*id;
            float i21 = (m01*m20 - m00*m21)*id;
            float i22 = (m00*m11 - m01*m10)*id;
            float px = pix2d[row*2+0], py = pix2d[row*2+1];
            float e0 = i00*px + i01*py + i02;
            float e1 = i10*px + i11*py + i12;
            float e2 = i20*px + i21*py + i22;
            float nb = fmaxf(sqrtf(e0*e0 + e1*e1 + e2*e2), 1e-12f);
            xin[3] = e1/nb; xin[4] = e0/nb; xin[5] = e2/nb;
        } else {
            float a0 = sn3d[row*3+0], a1 = sn3d[row*3+1], a2 = sn3d[row*3+2];
            float n = fmaxf(sqrtf(a0*a0 + a1*a1 + a2*a2), 1e-12f);
            xin[0] = a0/n; xin[1] = a1/n; xin[2] = a2/n;
            float p0 = pts3d[row*3+0], p1 = pts3d[row*3+1], p2 = pts3d[row*3+2];
            float pn = fmaxf(sqrtf(p0*p0 + p1*p1 + p2*p2), 1e-12f);
            xin[3] = p0/pn; xin[4] = p1/pn; xin[5] = p2/pn;
        }
    }
    __syncthreads();
    if (tid < 64) {
        float a = B1[tid];
        #pragma unroll
        for (int k = 0; k < 6; ++k) a += xin[k] * W1[tid*6 + k];
        h1s[tid] = sigmoidf_(a);
    }
    __syncthreads();
    {
        float a = B2[tid];
        #pragma unroll 8
        for (int k = 0; k < 64; ++k) a += h1s[k] * W2[tid*64 + k];
        h2s[tid] = sigmoidf_(a);
    }
    __syncthreads();
    float a = B3[tid];
    #pragma unroll 8
    for (int k = 0; k < 128; ++k) a += h2s[k] * W3[tid*128 + k];
    float o = sigmoidf_(a);

    float ss = o*o;
    #pragma unroll
    for (int m = 32; m >= 1; m >>= 1) ss += __shfl_xor(ss, m, 64);
    if ((tid & 63) == 0) red[tid >> 6] = ss;
    __syncthreads();
    float tot = red[0] + red[1];
    float n = fmaxf(sqrtf(tot), 1e-12f);
    float f = o / n;
    (side ? f3d : f2d)[row*FD + tid] = f;

    float ss2 = f*f;
    #pragma unroll
    for (int m = 32; m >= 1; m >>= 1) ss2 += __shfl_xor(ss2, m, 64);
    __syncthreads();
    if ((tid & 63) == 0) red[tid >> 6] = ss2;
    __syncthreads();
    if (tid == 0) (side ? y2 : x2)[row] = red[0] + red[1];
}

// ---------------- cost kernel: 64x64 tile; writes fp32 K, bf16 Kb (row), bf16 KbT (col), zeroes barrier ----------------
__global__ void __launch_bounds__(256) cost_kernel(const float* __restrict__ f2d, const float* __restrict__ f3d,
                                                   const float* __restrict__ x2, const float* __restrict__ y2,
                                                   float* __restrict__ K,
                                                   unsigned short* __restrict__ Kb,
                                                   unsigned short* __restrict__ KbT,
                                                   unsigned* __restrict__ bar,
                                                   int wantB, int wantT)
{
    __shared__ float As[128][64];
    __shared__ float Bs[128][64];
    const int tid = threadIdx.x;
    const int i0 = blockIdx.y * 64;
    const int j0 = blockIdx.x * 64;

    if (bar && blockIdx.x == 0 && blockIdx.y == 0 && tid == 0) *bar = 0u;

    {
        int r0 = tid >> 5;
        int c  = (tid & 31) * 4;
        for (int rr = r0; rr < 64; rr += 8) {
            float4 av = *(const float4*)(f2d + (size_t)(i0+rr)*FD + c);
            As[c+0][rr] = av.x; As[c+1][rr] = av.y; As[c+2][rr] = av.z; As[c+3][rr] = av.w;
            float4 bv = *(const float4*)(f3d + (size_t)(j0+rr)*FD + c);
            Bs[c+0][rr] = bv.x; Bs[c+1][rr] = bv.y; Bs[c+2][rr] = bv.z; Bs[c+3][rr] = bv.w;
        }
    }
    __syncthreads();

    const int tx = tid & 15;
    const int ty = tid >> 4;
    float acc[4][4] = {};
    for (int k = 0; k < 128; ++k) {
        float4 av = *(const float4*)&As[k][ty*4];
        float4 bv = *(const float4*)&Bs[k][tx*4];
        float aa[4] = {av.x, av.y, av.z, av.w};
        float bb[4] = {bv.x, bv.y, bv.z, bv.w};
        #pragma unroll
        for (int i = 0; i < 4; ++i)
            #pragma unroll
            for (int j = 0; j < 4; ++j)
                acc[i][j] += aa[i] * bb[j];
    }

    float kv[4][4];
    #pragma unroll
    for (int i = 0; i < 4; ++i) {
        int gi = i0 + ty*4 + i;
        float xv = x2[gi];
        #pragma unroll
        for (int j = 0; j < 4; ++j) {
            int gj = j0 + tx*4 + j;
            float d2 = xv + y2[gj] - 2.0f * acc[i][j];
            d2 = fmaxf(d2, 1e-12f);
            kv[i][j] = expf(-sqrtf(d2) * 10.0f);
        }
    }

    #pragma unroll
    for (int i = 0; i < 4; ++i) {
        int gi = i0 + ty*4 + i;
        *(float4*)(K + (size_t)gi*NPTS + j0 + tx*4) = make_float4(kv[i][0], kv[i][1], kv[i][2], kv[i][3]);
        if (wantB) {
            uint32 lo = (uint32)f2bf(kv[i][0]) | ((uint32)f2bf(kv[i][1]) << 16);
            uint32 hi = (uint32)f2bf(kv[i][2]) | ((uint32)f2bf(kv[i][3]) << 16);
            uint2 p; p.x = lo; p.y = hi;
            *(uint2*)(Kb + (size_t)gi*NPTS + j0 + tx*4) = p;
        }
    }
    if (wantT) {
        #pragma unroll
        for (int j = 0; j < 4; ++j) {
            int gj = j0 + tx*4 + j;
            uint32 lo = (uint32)f2bf(kv[0][j]) | ((uint32)f2bf(kv[1][j]) << 16);
            uint32 hi = (uint32)f2bf(kv[2][j]) | ((uint32)f2bf(kv[3][j]) << 16);
            uint2 p; p.x = lo; p.y = hi;
            *(uint2*)(KbT + (size_t)gj*NPTS + i0 + ty*4) = p;
        }
    }
}

// ---------------- persistent cooperative Sinkhorn: 256 blocks x 1024 thr, Kb rows in LDS ----------------
__global__ void __launch_bounds__(1024) sinkhorn_kernel(float* __restrict__ K,
                                                        const unsigned short* __restrict__ Kb,
                                                        const unsigned short* __restrict__ KbT,
                                                        float* __restrict__ u,
                                                        float* __restrict__ v,
                                                        unsigned* __restrict__ bar)
{
    extern __shared__ char smem[];
    float* xs = (float*)smem;                               // 16 KB staged u or v
    unsigned short* kbl = (unsigned short*)(smem + NPTS*4); // 128 KB: this block's 16 Kb rows

    const int tid  = threadIdx.x;
    const int w    = tid >> 6;
    const int lane = tid & 63;
    const int r    = blockIdx.x * 16 + w;

    // one-time: stage my 16 Kb rows into LDS (131072 B)
    {
        const float4* src = (const float4*)(Kb + (size_t)blockIdx.x * 16 * NPTS);
        float4* dst = (float4*)kbl;
        #pragma unroll
        for (int i = 0; i < 8; ++i) dst[tid + 1024*i] = src[tid + 1024*i];
    }

    float u_reg = 1.0f;

    for (int it = 0; it <= NITER; ++it) {
        // ---- stage u (or ones) into xs via coherent loads ----
        if (it == 0) {
            for (int i = tid; i < NPTS; i += 1024) xs[i] = 1.0f;
        } else {
            unsigned long long* xp = (unsigned long long*)xs;
            const unsigned long long* gp = (const unsigned long long*)u;
            #pragma unroll
            for (int i = 0; i < 2; ++i)
                xp[tid + 1024*i] = __hip_atomic_load(&gp[tid + 1024*i],
                                       __ATOMIC_RELAXED, __HIP_MEMORY_SCOPE_AGENT);
        }
        __syncthreads();

        // ---- half A: v_r = c / dot(K[:,r], u) — stream KbT row r from global ----
        {
            float acc = dot_bf16_g(KbT + (size_t)r * NPTS, xs, lane);
            acc = wave_red_sum(acc);
            if (lane == 0)
                __hip_atomic_store(&v[r], INVN / acc, __ATOMIC_RELAXED, __HIP_MEMORY_SCOPE_AGENT);
        }
        gbar(bar, tid);
        if (it == NITER) break;

        // ---- stage v into xs ----
        {
            unsigned long long* xp = (unsigned long long*)xs;
            const unsigned long long* gp = (const unsigned long long*)v;
            #pragma unroll
            for (int i = 0; i < 2; ++i)
                xp[tid + 1024*i] = __hip_atomic_load(&gp[tid + 1024*i],
                                       __ATOMIC_RELAXED, __HIP_MEMORY_SCOPE_AGENT);
        }
        __syncthreads();

        // ---- half B: u_r = r / dot(K[r,:], v) — Kb row w from LDS ----
        {
            const uint4* kp = (const uint4*)(kbl + w * NPTS);
            float acc = 0.0f;
            #pragma unroll
            for (int s = 0; s < 8; ++s) {
                int c = s * 64 + lane;
                uint4 kk = kp[c];
                const float* xp2 = xs + c * 8;
                float4 x0 = *(const float4*)xp2;
                float4 x1 = *(const float4*)(xp2 + 4);
                float xx[8] = {x0.x, x0.y, x0.z, x0.w, x1.x, x1.y, x1.z, x1.w};
                uint32 kw[4] = {kk.x, kk.y, kk.z, kk.w};
                #pragma unroll
                for (int q = 0; q < 4; ++q) {
                    acc += __uint_as_float(kw[q] << 16)         * xx[2*q]
                         + __uint_as_float(kw[q] & 0xffff0000u) * xx[2*q+1];
                }
            }
            acc = wave_red_sum(acc);
            u_reg = INVN / acc;          // butterfly reduce -> valid in all lanes
            if (lane == 0)
                __hip_atomic_store(&u[r], u_reg, __ATOMIC_RELAXED, __HIP_MEMORY_SCOPE_AGENT);
        }
        gbar(bar, tid);
    }

    // ---- final: P = u[:,None] * K * v[None,:] in place over d_out (fp32 K, exact) ----
    {
        unsigned long long* xp = (unsigned long long*)xs;
        const unsigned long long* gp = (const unsigned long long*)v;
        #pragma unroll
        for (int i = 0; i < 2; ++i)
            xp[tid + 1024*i] = __hip_atomic_load(&gp[tid + 1024*i],
                                   __ATOMIC_RELAXED, __HIP_MEMORY_SCOPE_AGENT);
        __syncthreads();
        const float ur = u_reg;
        float4* kp = (float4*)(K + (size_t)r * NPTS);
        #pragma unroll
        for (int s = 0; s < 16; ++s) {
            int e4 = s * 64 + lane;
            float4 kk = kp[e4];
            const float4 vv = *(const float4*)&xs[e4 * 4];
            kk.x *= ur * vv.x; kk.y *= ur * vv.y; kk.z *= ur * vv.z; kk.w *= ur * vv.w;
            kp[e4] = kk;
        }
    }
}

// ---------------- non-cooperative fallback kernels (used only if coop launch fails) ----------------
__global__ void __launch_bounds__(1024) stepA_kernel(const float* __restrict__ K,
                                                     const unsigned short* __restrict__ KbT,
                                                     const float* __restrict__ u, float* __restrict__ v,
                                                     int first, int modeA)
{
    const int w = threadIdx.x >> 6, lane = threadIdx.x & 63;
    const int r = blockIdx.x * 16 + w;
    float acc = modeA ? bf16_row_dot(KbT + (size_t)r * NPTS, u, lane, first)
                      : f32_col_dot(K, u, r, lane, first);
    acc = wave_red_sum(acc);
    if (lane == 0) v[r] = INVN / acc;
}

__global__ void __launch_bounds__(1024) stepB_kernel(const float* __restrict__ K,
                                                     const unsigned short* __restrict__ Kb,
                                                     const float* __restrict__ v, float* __restrict__ u,
                                                     int modeB)
{
    const int w = threadIdx.x >> 6, lane = threadIdx.x & 63;
    const int r = blockIdx.x * 16 + w;
    float acc = modeB ? bf16_row_dot(Kb + (size_t)r * NPTS, v, lane, 0)
                      : f32_row_dot(K + (size_t)r * NPTS, v, lane);
    acc = wave_red_sum(acc);
    if (lane == 0) u[r] = INVN / acc;
}

__global__ void __launch_bounds__(1024) final_kernel(float* __restrict__ K,
                                                     const float* __restrict__ u,
                                                     const float* __restrict__ v)
{
    const int w = threadIdx.x >> 6, lane = threadIdx.x & 63;
    const int r = blockIdx.x * 16 + w;
    const float ur = u[r];
    float4* kp = (float4*)(K + (size_t)r * NPTS);
    const float4* vp = (const float4*)v;
    #pragma unroll
    for (int s = 0; s < 16; ++s) {
        int e4 = s * 64 + lane;
        float4 kk = kp[e4], vv = vp[e4];
        kk.x *= ur * vv.x; kk.y *= ur * vv.y; kk.z *= ur * vv.z; kk.w *= ur * vv.w;
        kp[e4] = kk;
    }
}

extern "C" void kernel_launch(void* const* d_in, const int* in_sizes, int n_in,
                              void* d_out, int out_size, void* d_ws, size_t ws_size,
                              hipStream_t stream)
{
    (void)in_sizes; (void)n_in; (void)out_size;
    const float* sn2d  = (const float*)d_in[0];
    const float* sn3d  = (const float*)d_in[1];
    const float* pix2d = (const float*)d_in[2];
    const float* pts3d = (const float*)d_in[3];
    const float* intr  = (const float*)d_in[4];
    const float* W1i = (const float*)d_in[5];  const float* b1i = (const float*)d_in[6];
    const float* W2i = (const float*)d_in[7];  const float* b2i = (const float*)d_in[8];
    const float* W3i = (const float*)d_in[9];  const float* b3i = (const float*)d_in[10];
    const float* W1p = (const float*)d_in[11]; const float* b1p = (const float*)d_in[12];
    const float* W2p = (const float*)d_in[13]; const float* b2p = (const float*)d_in[14];
    const float* W3p = (const float*)d_in[15]; const float* b3p = (const float*)d_in[16];

    float* ws  = (float*)d_ws;
    float* f2d = ws;                       // 4096*128
    float* f3d = f2d + NPTS*FD;            // 4096*128
    float* x2  = f3d + NPTS*FD;            // 4096
    float* y2  = x2 + NPTS;                // 4096
    float* u   = y2 + NPTS;                // 4096
    float* v   = u  + NPTS;                // 4096
    unsigned short* KbT = (unsigned short*)(v + NPTS);   // 33.55 MB
    unsigned short* Kb  = KbT + (size_t)NPTS*NPTS;       // 33.55 MB
    unsigned* bar = (unsigned*)(Kb + (size_t)NPTS*NPTS); // barrier word (+pad)
    float* K   = (float*)d_out;            // fp32 K, scaled in place to P at the end

    const size_t base_bytes = (size_t)(2*NPTS*FD + 4*NPTS) * 4;
    const size_t bf16_bytes = (size_t)NPTS * NPTS * 2;
    const size_t need_full  = base_bytes + 2*bf16_bytes + 256;
    int coop_ok = (ws_size >= need_full) ? 1 : 0;
    int modeA = (ws_size >= base_bytes + bf16_bytes)   ? 1 : 0;
    int modeB = (ws_size >= base_bytes + 2*bf16_bytes) ? 1 : 0;

    feat_kernel<<<dim3(NPTS, 2), 128, 0, stream>>>(sn2d, sn3d, pix2d, pts3d, intr,
        W1i, b1i, W2i, b2i, W3i, b3i, W1p, b1p, W2p, b2p, W3p, b3p,
        f2d, f3d, x2, y2);

    cost_kernel<<<dim3(64, 64), 256, 0, stream>>>(f2d, f3d, x2, y2, K, Kb, KbT,
                                                  coop_ok ? bar : (unsigned*)0,
                                                  modeB, modeA);

    hipError_t err = hipErrorUnknown;
    if (coop_ok) {
        (void)hipFuncSetAttribute((const void*)sinkhorn_kernel,
                                  hipFuncAttributeMaxDynamicSharedMemorySize, SMEM_BYTES);
        void* args[] = { (void*)&K, (void*)&Kb, (void*)&KbT, (void*)&u, (void*)&v, (void*)&bar };
        err = hipLaunchCooperativeKernel((const void*)sinkhorn_kernel,
                                         dim3(NBLK), dim3(1024), args, SMEM_BYTES, stream);
    }
    if (err != hipSuccess) {
        // non-cooperative fallback: same math, one launch per half-step
        stepA_kernel<<<256, 1024, 0, stream>>>(K, KbT, u, v, 1, modeA);
        for (int i = 0; i < NITER; ++i) {
            stepB_kernel<<<256, 1024, 0, stream>>>(K, Kb, v, u, modeB);
            stepA_kernel<<<256, 1024, 0, stream>>>(K, KbT, u, v, 0, modeA);
        }
        final_kernel<<<256, 1024, 0, stream>>>(K, u, v);
    }
}

// Round 5
// 2470.313 us; speedup vs baseline: 7.2274x; 1.1930x over previous
//
#include <hip/hip_runtime.h>
#include <math.h>

#define NPTS 4096
#define FD   128
#define NITER 200
#define INVN (1.0f / 4096.0f)
#define NBLK 256
#define NGRP 16
#define GRPSZ (NBLK / NGRP)
#define SMEM_BYTES (NPTS*4 + 16*NPTS*2)   // 16 KB xs + 128 KB Kb rows = 147456 B

typedef unsigned int uint32;

__device__ __forceinline__ float sigmoidf_(float x) { return 1.0f / (1.0f + expf(-x)); }

__device__ __forceinline__ unsigned short f2bf(float f) {
    uint32 x = __float_as_uint(f);
    uint32 r = x + 0x7fffu + ((x >> 16) & 1u);   // RNE; inputs are positive finite
    return (unsigned short)(r >> 16);
}

__device__ __forceinline__ float wave_red_sum(float a) {
    #pragma unroll
    for (int m = 32; m >= 1; m >>= 1) a += __shfl_xor(a, m, 64);
    return a;
}

// 16-B-group XOR swizzle for xs: spreads 32 B/lane-stride reads over all bank groups
__device__ __forceinline__ int swz(int g) { return g ^ ((g >> 3) & 7); }

// ---- hierarchical grid barrier: root + 16 group words (gen<<8 | count), 256 B apart ----
// bar[0] = root; bar[64*(1+g)] = group g. No L2 flush; agent-scope relaxed atomics only.
__device__ __forceinline__ void gbar(unsigned* bar, int tid, int bid) {
    asm volatile("s_waitcnt vmcnt(0)" ::: "memory");   // drain this wave's coherent stores
    __syncthreads();                                   // all waves drained + arrived
    if (tid == 0) {
        unsigned* grp = bar + 64 * (1 + (bid >> 4));
        unsigned old = __hip_atomic_fetch_add(grp, 1u, __ATOMIC_RELAXED, __HIP_MEMORY_SCOPE_AGENT);
        unsigned gen = old >> 8;
        if ((old & 0xFFu) == (unsigned)(GRPSZ - 1)) {
            // last in group -> arrive at root
            unsigned rold = __hip_atomic_fetch_add(bar, 1u, __ATOMIC_RELAXED, __HIP_MEMORY_SCOPE_AGENT);
            unsigned rgen = rold >> 8;
            if ((rold & 0xFFu) == (unsigned)(NGRP - 1)) {
                // root release: bump gen, reset count in one atomic
                __hip_atomic_fetch_add(bar, (1u << 8) - (unsigned)NGRP,
                                       __ATOMIC_RELAXED, __HIP_MEMORY_SCOPE_AGENT);
            } else {
                int guard = 0;
                while ((__hip_atomic_load(bar, __ATOMIC_RELAXED, __HIP_MEMORY_SCOPE_AGENT) >> 8) == rgen) {
                    __builtin_amdgcn_s_sleep(1);
                    if (++guard > (1 << 24)) break;
                }
            }
            // propagate to my group: bump gen, reset count
            __hip_atomic_fetch_add(grp, (1u << 8) - (unsigned)GRPSZ,
                                   __ATOMIC_RELAXED, __HIP_MEMORY_SCOPE_AGENT);
        } else {
            int guard = 0;
            while ((__hip_atomic_load(grp, __ATOMIC_RELAXED, __HIP_MEMORY_SCOPE_AGENT) >> 8) == gen) {
                __builtin_amdgcn_s_sleep(1);
                if (++guard > (1 << 24)) break;
            }
        }
    }
    __syncthreads();
}

// per-lane partial of dot(bf16 row in GLOBAL, swizzled xs in LDS); caller wave-reduces
__device__ __forceinline__ float dot_bf16_g(const unsigned short* __restrict__ Krow,
                                            const float* xs, int lane)
{
    const uint4* kp = (const uint4*)Krow;
    float acc = 0.0f;
    #pragma unroll
    for (int s = 0; s < 8; ++s) {
        int c = s * 64 + lane;
        uint4 kk = kp[c];
        int g0 = 2 * c, g1 = 2 * c + 1;
        float4 x0 = *(const float4*)((const char*)xs + 16 * swz(g0));
        float4 x1 = *(const float4*)((const char*)xs + 16 * swz(g1));
        float xx[8] = {x0.x, x0.y, x0.z, x0.w, x1.x, x1.y, x1.z, x1.w};
        uint32 kw[4] = {kk.x, kk.y, kk.z, kk.w};
        #pragma unroll
        for (int q = 0; q < 4; ++q) {
            acc += __uint_as_float(kw[q] << 16)          * xx[2*q]
                 + __uint_as_float(kw[q] & 0xffff0000u)  * xx[2*q+1];
        }
    }
    return acc;
}

// round-3 helpers for the non-cooperative fallback path
__device__ __forceinline__ float bf16_row_dot(const unsigned short* __restrict__ Krow,
                                              const float* __restrict__ x,
                                              int lane, int first)
{
    const float4* kp = (const float4*)Krow;
    const float4* xp = (const float4*)x;
    float acc = 0.0f;
    #pragma unroll
    for (int s = 0; s < 8; ++s) {
        int i = s*64 + lane;
        float4 kk = kp[i];
        const uint32* kw = (const uint32*)&kk;
        float xx[8];
        if (first) {
            #pragma unroll
            for (int q = 0; q < 8; ++q) xx[q] = 1.0f;
        } else {
            float4 x0 = xp[i*2], x1 = xp[i*2 + 1];
            xx[0]=x0.x; xx[1]=x0.y; xx[2]=x0.z; xx[3]=x0.w;
            xx[4]=x1.x; xx[5]=x1.y; xx[6]=x1.z; xx[7]=x1.w;
        }
        #pragma unroll
        for (int q = 0; q < 4; ++q) {
            acc += __uint_as_float(kw[q] << 16)         * xx[2*q]
                 + __uint_as_float(kw[q] & 0xffff0000u) * xx[2*q+1];
        }
    }
    return acc;
}

__device__ __forceinline__ float f32_row_dot(const float* __restrict__ Krow,
                                             const float* __restrict__ x, int lane)
{
    const float4* kp = (const float4*)Krow;
    const float4* xp = (const float4*)x;
    float acc = 0.0f;
    #pragma unroll
    for (int s = 0; s < 16; ++s) {
        int i = s*64 + lane;
        float4 kk = kp[i], xx = xp[i];
        acc += kk.x*xx.x + kk.y*xx.y + kk.z*xx.z + kk.w*xx.w;
    }
    return acc;
}

__device__ __forceinline__ float f32_col_dot(const float* __restrict__ K,
                                             const float* __restrict__ u,
                                             int col, int lane, int first)
{
    float acc = 0.0f;
    for (int i = lane; i < NPTS; i += 64)
        acc += K[(size_t)i*NPTS + col] * (first ? 1.0f : u[i]);
    return acc;
}

// ---------------- feature MLP kernel: one block (128 thr) per row, side = blockIdx.y ----------------
__global__ void feat_kernel(const float* __restrict__ sn2d, const float* __restrict__ sn3d,
                            const float* __restrict__ pix2d, const float* __restrict__ pts3d,
                            const float* __restrict__ intr,
                            const float* __restrict__ W1i, const float* __restrict__ b1i,
                            const float* __restrict__ W2i, const float* __restrict__ b2i,
                            const float* __restrict__ W3i, const float* __restrict__ b3i,
                            const float* __restrict__ W1p, const float* __restrict__ b1p,
                            const float* __restrict__ W2p, const float* __restrict__ b2p,
                            const float* __restrict__ W3p, const float* __restrict__ b3p,
                            float* __restrict__ f2d, float* __restrict__ f3d,
                            float* __restrict__ x2, float* __restrict__ y2)
{
    const int row  = blockIdx.x;
    const int side = blockIdx.y;
    const int tid  = threadIdx.x;

    __shared__ float xin[6];
    __shared__ float h1s[64];
    __shared__ float h2s[128];
    __shared__ float red[2];

    const float* W1 = side ? W1p : W1i;  const float* B1 = side ? b1p : b1i;
    const float* W2 = side ? W2p : W2i;  const float* B2 = side ? b2p : b2i;
    const float* W3 = side ? W3p : W3i;  const float* B3 = side ? b3p : b3i;

    if (tid == 0) {
        if (side == 0) {
            float a0 = sn2d[row*3+0], a1 = sn2d[row*3+1], a2 = sn2d[row*3+2];
            float n = fmaxf(sqrtf(a0*a0 + a1*a1 + a2*a2), 1e-12f);
            xin[0] = a0/n; xin[1] = a1/n; xin[2] = a2/n;
            float m00 = intr[0], m01 = intr[1], m02 = intr[2];
            float m10 = intr[3], m11 = intr[4], m12 = intr[5];
            float m20 = intr[6], m21 = intr[7], m22 = intr[8];
            float det = m00*(m11*m22 - m12*m21) - m01*(m10*m22 - m12*m20) + m02*(m10*m21 - m11*m20);
            float id = 1.0f/det;
            float i00 = (m11*m22 - m12*m21)*id;
            float i01 = (m02*m21 - m01*m22)*id;
            float i02 = (m01*m12 - m02*m11)*id;
            float i10 = (m12*m20 - m10*m22)*id;
            float i11 = (m00*m22 - m02*m20)*id;
            float i12 = (m02*m10 - m00*m12)*id;
            float i20 = (m10*m21 - m11*m20)*id;
            float i21 = (m01*m20 - m00*m21)*id;
            float i22 = (m00*m11 - m01*m10)*id;
            float px = pix2d[row*2+0], py = pix2d[row*2+1];
            float e0 = i00*px + i01*py + i02;
            float e1 = i10*px + i11*py + i12;
            float e2 = i20*px + i21*py + i22;
            float nb = fmaxf(sqrtf(e0*e0 + e1*e1 + e2*e2), 1e-12f);
            xin[3] = e1/nb; xin[4] = e0/nb; xin[5] = e2/nb;
        } else {
            float a0 = sn3d[row*3+0], a1 = sn3d[row*3+1], a2 = sn3d[row*3+2];
            float n = fmaxf(sqrtf(a0*a0 + a1*a1 + a2*a2), 1e-12f);
            xin[0] = a0/n; xin[1] = a1/n; xin[2] = a2/n;
            float p0 = pts3d[row*3+0], p1 = pts3d[row*3+1], p2 = pts3d[row*3+2];
            float pn = fmaxf(sqrtf(p0*p0 + p1*p1 + p2*p2), 1e-12f);
            xin[3] = p0/pn; xin[4] = p1/pn; xin[5] = p2/pn;
        }
    }
    __syncthreads();
    if (tid < 64) {
        float a = B1[tid];
        #pragma unroll
        for (int k = 0; k < 6; ++k) a += xin[k] * W1[tid*6 + k];
        h1s[tid] = sigmoidf_(a);
    }
    __syncthreads();
    {
        float a = B2[tid];
        #pragma unroll 8
        for (int k = 0; k < 64; ++k) a += h1s[k] * W2[tid*64 + k];
        h2s[tid] = sigmoidf_(a);
    }
    __syncthreads();
    float a = B3[tid];
    #pragma unroll 8
    for (int k = 0; k < 128; ++k) a += h2s[k] * W3[tid*128 + k];
    float o = sigmoidf_(a);

    float ss = o*o;
    #pragma unroll
    for (int m = 32; m >= 1; m >>= 1) ss += __shfl_xor(ss, m, 64);
    if ((tid & 63) == 0) red[tid >> 6] = ss;
    __syncthreads();
    float tot = red[0] + red[1];
    float n = fmaxf(sqrtf(tot), 1e-12f);
    float f = o / n;
    (side ? f3d : f2d)[row*FD + tid] = f;

    float ss2 = f*f;
    #pragma unroll
    for (int m = 32; m >= 1; m >>= 1) ss2 += __shfl_xor(ss2, m, 64);
    __syncthreads();
    if ((tid & 63) == 0) red[tid >> 6] = ss2;
    __syncthreads();
    if (tid == 0) (side ? y2 : x2)[row] = red[0] + red[1];
}

// ---------------- cost kernel: 64x64 tile; writes fp32 K, bf16 Kb (row), bf16 KbT (col), inits barrier ----------------
__global__ void __launch_bounds__(256) cost_kernel(const float* __restrict__ f2d, const float* __restrict__ f3d,
                                                   const float* __restrict__ x2, const float* __restrict__ y2,
                                                   float* __restrict__ K,
                                                   unsigned short* __restrict__ Kb,
                                                   unsigned short* __restrict__ KbT,
                                                   unsigned* __restrict__ bar,
                                                   int wantB, int wantT)
{
    __shared__ float As[128][64];
    __shared__ float Bs[128][64];
    const int tid = threadIdx.x;
    const int i0 = blockIdx.y * 64;
    const int j0 = blockIdx.x * 64;

    if (bar && blockIdx.x == 0 && blockIdx.y == 0 && tid < 1 + NGRP)
        __hip_atomic_store(&bar[tid * 64], 0u, __ATOMIC_RELAXED, __HIP_MEMORY_SCOPE_AGENT);

    {
        int r0 = tid >> 5;
        int c  = (tid & 31) * 4;
        for (int rr = r0; rr < 64; rr += 8) {
            float4 av = *(const float4*)(f2d + (size_t)(i0+rr)*FD + c);
            As[c+0][rr] = av.x; As[c+1][rr] = av.y; As[c+2][rr] = av.z; As[c+3][rr] = av.w;
            float4 bv = *(const float4*)(f3d + (size_t)(j0+rr)*FD + c);
            Bs[c+0][rr] = bv.x; Bs[c+1][rr] = bv.y; Bs[c+2][rr] = bv.z; Bs[c+3][rr] = bv.w;
        }
    }
    __syncthreads();

    const int tx = tid & 15;
    const int ty = tid >> 4;
    float acc[4][4] = {};
    for (int k = 0; k < 128; ++k) {
        float4 av = *(const float4*)&As[k][ty*4];
        float4 bv = *(const float4*)&Bs[k][tx*4];
        float aa[4] = {av.x, av.y, av.z, av.w};
        float bb[4] = {bv.x, bv.y, bv.z, bv.w};
        #pragma unroll
        for (int i = 0; i < 4; ++i)
            #pragma unroll
            for (int j = 0; j < 4; ++j)
                acc[i][j] += aa[i] * bb[j];
    }

    float kv[4][4];
    #pragma unroll
    for (int i = 0; i < 4; ++i) {
        int gi = i0 + ty*4 + i;
        float xv = x2[gi];
        #pragma unroll
        for (int j = 0; j < 4; ++j) {
            int gj = j0 + tx*4 + j;
            float d2 = xv + y2[gj] - 2.0f * acc[i][j];
            d2 = fmaxf(d2, 1e-12f);
            kv[i][j] = expf(-sqrtf(d2) * 10.0f);
        }
    }

    #pragma unroll
    for (int i = 0; i < 4; ++i) {
        int gi = i0 + ty*4 + i;
        *(float4*)(K + (size_t)gi*NPTS + j0 + tx*4) = make_float4(kv[i][0], kv[i][1], kv[i][2], kv[i][3]);
        if (wantB) {
            uint32 lo = (uint32)f2bf(kv[i][0]) | ((uint32)f2bf(kv[i][1]) << 16);
            uint32 hi = (uint32)f2bf(kv[i][2]) | ((uint32)f2bf(kv[i][3]) << 16);
            uint2 p; p.x = lo; p.y = hi;
            *(uint2*)(Kb + (size_t)gi*NPTS + j0 + tx*4) = p;
        }
    }
    if (wantT) {
        #pragma unroll
        for (int j = 0; j < 4; ++j) {
            int gj = j0 + tx*4 + j;
            uint32 lo = (uint32)f2bf(kv[0][j]) | ((uint32)f2bf(kv[1][j]) << 16);
            uint32 hi = (uint32)f2bf(kv[2][j]) | ((uint32)f2bf(kv[3][j]) << 16);
            uint2 p; p.x = lo; p.y = hi;
            *(uint2*)(KbT + (size_t)gj*NPTS + i0 + ty*4) = p;
        }
    }
}

// ---------------- persistent cooperative Sinkhorn: 256 blocks x 1024 thr, Kb rows in LDS ----------------
__global__ void __launch_bounds__(1024) sinkhorn_kernel(float* __restrict__ K,
                                                        const unsigned short* __restrict__ Kb,
                                                        const unsigned short* __restrict__ KbT,
                                                        float* __restrict__ u,
                                                        float* __restrict__ v,
                                                        unsigned* __restrict__ bar)
{
    extern __shared__ char smem[];
    float* xs = (float*)smem;                               // 16 KB staged u or v (swizzled)
    unsigned short* kbl = (unsigned short*)(smem + NPTS*4); // 128 KB: this block's 16 Kb rows

    const int tid  = threadIdx.x;
    const int w    = tid >> 6;
    const int lane = tid & 63;
    const int bid  = blockIdx.x;
    const int r    = bid * 16 + w;

    // one-time: stage my 16 Kb rows into LDS (131072 B)
    {
        const float4* src = (const float4*)(Kb + (size_t)bid * 16 * NPTS);
        float4* dst = (float4*)kbl;
        #pragma unroll
        for (int i = 0; i < 8; ++i) dst[tid + 1024*i] = src[tid + 1024*i];
    }

    float u_reg = 1.0f;

    for (int it = 0; it <= NITER; ++it) {
        // ---- stage u (or ones) into swizzled xs via coherent loads ----
        if (it == 0) {
            for (int i = tid; i < NPTS; i += 1024) xs[i] = 1.0f;   // all-ones: swizzle-invariant
        } else {
            const unsigned long long* gp = (const unsigned long long*)u;
            #pragma unroll
            for (int i = 0; i < 2; ++i) {
                int idx = tid + 1024*i;
                unsigned long long val = __hip_atomic_load(&gp[idx],
                                             __ATOMIC_RELAXED, __HIP_MEMORY_SCOPE_AGENT);
                int g = idx >> 1;
                *(unsigned long long*)((char*)xs + 16*swz(g) + (idx & 1)*8) = val;
            }
        }
        __syncthreads();

        // ---- half A: v_r = c / dot(K[:,r], u) — stream KbT row r from global ----
        {
            float acc = dot_bf16_g(KbT + (size_t)r * NPTS, xs, lane);
            acc = wave_red_sum(acc);
            if (lane == 0)
                __hip_atomic_store(&v[r], INVN / acc, __ATOMIC_RELAXED, __HIP_MEMORY_SCOPE_AGENT);
        }
        gbar(bar, tid, bid);
        if (it == NITER) break;

        // ---- stage v into swizzled xs ----
        {
            const unsigned long long* gp = (const unsigned long long*)v;
            #pragma unroll
            for (int i = 0; i < 2; ++i) {
                int idx = tid + 1024*i;
                unsigned long long val = __hip_atomic_load(&gp[idx],
                                             __ATOMIC_RELAXED, __HIP_MEMORY_SCOPE_AGENT);
                int g = idx >> 1;
                *(unsigned long long*)((char*)xs + 16*swz(g) + (idx & 1)*8) = val;
            }
        }
        __syncthreads();

        // ---- half B: u_r = r / dot(K[r,:], v) — Kb row w from LDS ----
        {
            const uint4* kp = (const uint4*)(kbl + w * NPTS);
            float acc = 0.0f;
            #pragma unroll
            for (int s = 0; s < 8; ++s) {
                int c = s * 64 + lane;
                uint4 kk = kp[c];
                float4 x0 = *(const float4*)((const char*)xs + 16*swz(2*c));
                float4 x1 = *(const float4*)((const char*)xs + 16*swz(2*c + 1));
                float xx[8] = {x0.x, x0.y, x0.z, x0.w, x1.x, x1.y, x1.z, x1.w};
                uint32 kw[4] = {kk.x, kk.y, kk.z, kk.w};
                #pragma unroll
                for (int q = 0; q < 4; ++q) {
                    acc += __uint_as_float(kw[q] << 16)         * xx[2*q]
                         + __uint_as_float(kw[q] & 0xffff0000u) * xx[2*q+1];
                }
            }
            acc = wave_red_sum(acc);
            u_reg = INVN / acc;          // butterfly reduce -> valid in all lanes
            if (lane == 0)
                __hip_atomic_store(&u[r], u_reg, __ATOMIC_RELAXED, __HIP_MEMORY_SCOPE_AGENT);
        }
        gbar(bar, tid, bid);
    }

    // ---- final: P = u[:,None] * K * v[None,:] in place over d_out (fp32 K, exact) ----
    {
        const unsigned long long* gp = (const unsigned long long*)v;
        #pragma unroll
        for (int i = 0; i < 2; ++i) {
            int idx = tid + 1024*i;
            unsigned long long val = __hip_atomic_load(&gp[idx],
                                         __ATOMIC_RELAXED, __HIP_MEMORY_SCOPE_AGENT);
            int g = idx >> 1;
            *(unsigned long long*)((char*)xs + 16*swz(g) + (idx & 1)*8) = val;
        }
        __syncthreads();
        const float ur = u_reg;
        float4* kp = (float4*)(K + (size_t)r * NPTS);
        #pragma unroll
        for (int s = 0; s < 16; ++s) {
            int e4 = s * 64 + lane;
            float4 kk = kp[e4];
            const float4 vv = *(const float4*)((const char*)xs + 16*swz(e4));
            kk.x *= ur * vv.x; kk.y *= ur * vv.y; kk.z *= ur * vv.z; kk.w *= ur * vv.w;
            kp[e4] = kk;
        }
    }
}

// ---------------- non-cooperative fallback kernels (used only if coop launch fails) ----------------
__global__ void __launch_bounds__(1024) stepA_kernel(const float* __restrict__ K,
                                                     const unsigned short* __restrict__ KbT,
                                                     const float* __restrict__ u, float* __restrict__ v,
                                                     int first, int modeA)
{
    const int w = threadIdx.x >> 6, lane = threadIdx.x & 63;
    const int r = blockIdx.x * 16 + w;
    float acc = modeA ? bf16_row_dot(KbT + (size_t)r * NPTS, u, lane, first)
                      : f32_col_dot(K, u, r, lane, first);
    acc = wave_red_sum(acc);
    if (lane == 0) v[r] = INVN / acc;
}

__global__ void __launch_bounds__(1024) stepB_kernel(const float* __restrict__ K,
                                                     const unsigned short* __restrict__ Kb,
                                                     const float* __restrict__ v, float* __restrict__ u,
                                                     int modeB)
{
    const int w = threadIdx.x >> 6, lane = threadIdx.x & 63;
    const int r = blockIdx.x * 16 + w;
    float acc = modeB ? bf16_row_dot(Kb + (size_t)r * NPTS, v, lane, 0)
                      : f32_row_dot(K + (size_t)r * NPTS, v, lane);
    acc = wave_red_sum(acc);
    if (lane == 0) u[r] = INVN / acc;
}

__global__ void __launch_bounds__(1024) final_kernel(float* __restrict__ K,
                                                     const float* __restrict__ u,
                                                     const float* __restrict__ v)
{
    const int w = threadIdx.x >> 6, lane = threadIdx.x & 63;
    const int r = blockIdx.x * 16 + w;
    const float ur = u[r];
    float4* kp = (float4*)(K + (size_t)r * NPTS);
    const float4* vp = (const float4*)v;
    #pragma unroll
    for (int s = 0; s < 16; ++s) {
        int e4 = s * 64 + lane;
        float4 kk = kp[e4], vv = vp[e4];
        kk.x *= ur * vv.x; kk.y *= ur * vv.y; kk.z *= ur * vv.z; kk.w *= ur * vv.w;
        kp[e4] = kk;
    }
}

extern "C" void kernel_launch(void* const* d_in, const int* in_sizes, int n_in,
                              void* d_out, int out_size, void* d_ws, size_t ws_size,
                              hipStream_t stream)
{
    (void)in_sizes; (void)n_in; (void)out_size;
    const float* sn2d  = (const float*)d_in[0];
    const float* sn3d  = (const float*)d_in[1];
    const float* pix2d = (const float*)d_in[2];
    const float* pts3d = (const float*)d_in[3];
    const float* intr  = (const float*)d_in[4];
    const float* W1i = (const float*)d_in[5];  const float* b1i = (const float*)d_in[6];
    const float* W2i = (const float*)d_in[7];  const float* b2i = (const float*)d_in[8];
    const float* W3i = (const float*)d_in[9];  const float* b3i = (const float*)d_in[10];
    const float* W1p = (const float*)d_in[11]; const float* b1p = (const float*)d_in[12];
    const float* W2p = (const float*)d_in[13]; const float* b2p = (const float*)d_in[14];
    const float* W3p = (const float*)d_in[15]; const float* b3p = (const float*)d_in[16];

    float* ws  = (float*)d_ws;
    float* f2d = ws;                       // 4096*128
    float* f3d = f2d + NPTS*FD;            // 4096*128
    float* x2  = f3d + NPTS*FD;            // 4096
    float* y2  = x2 + NPTS;                // 4096
    float* u   = y2 + NPTS;                // 4096
    float* v   = u  + NPTS;                // 4096
    unsigned short* KbT = (unsigned short*)(v + NPTS);   // 33.55 MB
    unsigned short* Kb  = KbT + (size_t)NPTS*NPTS;       // 33.55 MB
    unsigned* bar = (unsigned*)(Kb + (size_t)NPTS*NPTS); // root + 16 group words, 256 B apart
    float* K   = (float*)d_out;            // fp32 K, scaled in place to P at the end

    const size_t base_bytes = (size_t)(2*NPTS*FD + 4*NPTS) * 4;
    const size_t bf16_bytes = (size_t)NPTS * NPTS * 2;
    const size_t need_full  = base_bytes + 2*bf16_bytes + 8192;
    int coop_ok = (ws_size >= need_full) ? 1 : 0;
    int modeA = (ws_size >= base_bytes + bf16_bytes)   ? 1 : 0;
    int modeB = (ws_size >= base_bytes + 2*bf16_bytes) ? 1 : 0;

    feat_kernel<<<dim3(NPTS, 2), 128, 0, stream>>>(sn2d, sn3d, pix2d, pts3d, intr,
        W1i, b1i, W2i, b2i, W3i, b3i, W1p, b1p, W2p, b2p, W3p, b3p,
        f2d, f3d, x2, y2);

    cost_kernel<<<dim3(64, 64), 256, 0, stream>>>(f2d, f3d, x2, y2, K, Kb, KbT,
                                                  coop_ok ? bar : (unsigned*)0,
                                                  modeB, modeA);

    hipError_t err = hipErrorUnknown;
    if (coop_ok) {
        (void)hipFuncSetAttribute((const void*)sinkhorn_kernel,
                                  hipFuncAttributeMaxDynamicSharedMemorySize, SMEM_BYTES);
        void* args[] = { (void*)&K, (void*)&Kb, (void*)&KbT, (void*)&u, (void*)&v, (void*)&bar };
        err = hipLaunchCooperativeKernel((const void*)sinkhorn_kernel,
                                         dim3(NBLK), dim3(1024), args, SMEM_BYTES, stream);
    }
    if (err != hipSuccess) {
        // non-cooperative fallback: same math, one launch per half-step
        stepA_kernel<<<256, 1024, 0, stream>>>(K, KbT, u, v, 1, modeA);
        for (int i = 0; i < NITER; ++i) {
            stepB_kernel<<<256, 1024, 0, stream>>>(K, Kb, v, u, modeB);
            stepA_kernel<<<256, 1024, 0, stream>>>(K, KbT, u, v, 0, modeA);
        }
        final_kernel<<<256, 1024, 0, stream>>>(K, u, v);
    }
}